// Round 12
// baseline (664.628 us; speedup 1.0000x reference)
//
#include <hip/hip_runtime.h>
#include <hip/hip_bf16.h>

typedef __attribute__((ext_vector_type(8))) short s16x8;
typedef __attribute__((ext_vector_type(4))) float f32x4;

__device__ __forceinline__ unsigned short f2bf(float f){
    __hip_bfloat16 h = __float2bfloat16(f);
    return *reinterpret_cast<unsigned short*>(&h);
}

__device__ __forceinline__ int flab(int g){ return (g < 120) ? 0 : ((g < 124) ? 1 : 2); }

// async global->LDS, 16B per lane; LDS dest = wave-uniform base + lane*16
__device__ __forceinline__ void async16(const void* g, void* l){
    __builtin_amdgcn_global_load_lds(
        (const __attribute__((address_space(1))) unsigned int*)g,
        (__attribute__((address_space(3))) unsigned int*)l, 16, 0, 0);
}

// ---------------- weight fp32 -> bf16 (w1/w2 into blocked layouts) --------
// w1b[oc 0..3][ks 0..5][192][32]  (fc1_w 768x192; oc = 192-row chunk)
// w2b[q 0..3][ks 0..23][48][32]   (fc2_w 192x768)
__global__ __launch_bounds__(256) void wconv_all(
    const float* __restrict__ w0, const float* __restrict__ w1,
    const float* __restrict__ w2, const float* __restrict__ w3,
    unsigned short* __restrict__ o0, unsigned short* __restrict__ o1,
    unsigned short* __restrict__ o2, unsigned short* __restrict__ o3)
{
    int i = blockIdx.x*256 + threadIdx.x;
    if (i < 110592) o0[i] = f2bf(w0[i]);   // qkv_w 576x192
    if (i < 36864)  o1[i] = f2bf(w1[i]);   // proj_w 192x192
    if (i < 147456) {
        int o = i/192, k = i - o*192;
        int oc = o/192, r = o - oc*192, ks = k>>5, c = k&31;
        o2[((oc*6 + ks)*192 + r)*32 + c] = f2bf(w2[i]);
    }
    if (i < 147456) {
        int o = i/768, k = i - o*768;
        int q = o/48, r = o - q*48, ks = k>>5, c = k&31;
        o3[((q*24 + ks)*48 + r)*32 + c] = f2bf(w3[i]);
    }
}

// =====================================================================
// LN1 + shift + window partition + QKV GEMM, fused. One block per window.
// =====================================================================
__global__ __launch_bounds__(256) void lnqkv_kernel(
    const float* __restrict__ x, const float* __restrict__ g1, const float* __restrict__ b1,
    const unsigned short* __restrict__ wq, const float* __restrict__ qkvb,
    unsigned short* __restrict__ qo, unsigned short* __restrict__ ko,
    unsigned short* __restrict__ vo)
{
    __shared__ __attribute__((aligned(16))) unsigned short win[64*200];  // 25.6KB
    __shared__ __attribute__((aligned(16))) unsigned short Bs[64*200];   // 25.6KB (B-tile / T)
    const int b_ = blockIdx.x;
    const int bb = b_>>8, wi = b_&255, wh = wi>>4, ww = wi&15;
    const int tid = threadIdx.x;
    const int wv = tid>>6, lane = tid&63, lrow = lane&15, quad = lane>>4;

    // ---- LN1: thread t -> token n = t>>2, quarter q4 = t&3 (48 ch each) ----
    {
        const int n = tid>>2, q4 = tid&3;
        const int r = n>>3, c = n&7;
        const int hh = (wh*8 + r + 4)&127, wp = (ww*8 + c + 4)&127;  // roll(-4)
        const float* px = x + (((size_t)bb*128+hh)*128+wp)*192 + q4*48;
        float v[48];
        #pragma unroll
        for (int m=0;m<12;++m) *(float4*)(v+m*4) = *(const float4*)(px+m*4);
        float s = 0.f;
        #pragma unroll
        for (int k=0;k<48;++k) s += v[k];
        s += __shfl_xor(s,1); s += __shfl_xor(s,2);
        float mu = s*(1.0f/192.0f);
        float qv = 0.f;
        #pragma unroll
        for (int k=0;k<48;++k){ float d=v[k]-mu; qv += d*d; }
        qv += __shfl_xor(qv,1); qv += __shfl_xor(qv,2);
        float rstd = rsqrtf(qv*(1.0f/192.0f) + 1e-5f);
        const float* pg = g1 + q4*48;
        const float* pb = b1 + q4*48;
        unsigned short* pw = win + n*200 + q4*48;
        #pragma unroll
        for (int k=0;k<48;++k) pw[k] = f2bf((v[k]-mu)*rstd*pg[k] + pb[k]);
    }
    __syncthreads();

    // hoist A fragments (reused by every o-tile)
    s16x8 af[6];
    #pragma unroll
    for (int kc=0;kc<6;++kc)
        af[kc] = *(const s16x8*)(win + (wv*16+lrow)*200 + kc*32 + quad*8);

    for (int ot=0; ot<9; ++ot) {
        const int o0 = ot*64;
        __syncthreads();                       // Bs free (prev T reads done)
        #pragma unroll
        for (int t=0;t<6;++t) {
            int cid = tid + t*256;             // 0..1535, globally contiguous
            *(int4*)(Bs + (cid/24)*200 + (cid%24)*8) =
                *(const int4*)(wq + (size_t)o0*192 + cid*8);
        }
        __syncthreads();
        f32x4 acc[4];
        #pragma unroll
        for (int j=0;j<4;++j) acc[j] = (f32x4){0.f,0.f,0.f,0.f};
        #pragma unroll
        for (int kc=0;kc<6;++kc)
            #pragma unroll
            for (int j=0;j<4;++j) {
                s16x8 bf = *(const s16x8*)(Bs + (j*16+lrow)*200 + kc*32 + quad*8);
                acc[j] = __builtin_amdgcn_mfma_f32_16x16x32_bf16(af[kc], bf, acc[j], 0, 0, 0);
            }
        __syncthreads();                       // done reading Bs; reuse as T
        unsigned short* T = Bs;
        const int part = ot/3;                 // 0=q 1=k 2=v
        float bv[4];
        #pragma unroll
        for (int j=0;j<4;++j) bv[j] = qkvb[o0 + j*16 + lrow];

        if (part < 2) {
            const float scale = (part==0) ? 0.17677669529663687f : 1.0f;
            #pragma unroll
            for (int j=0;j<4;++j)
                #pragma unroll
                for (int rg=0;rg<4;++rg) {
                    int n2 = wv*16 + quad*4 + rg;
                    T[n2*72 + j*16 + lrow] = f2bf((acc[j][rg]+bv[j])*scale);
                }
            __syncthreads();
            unsigned short* dst = (part==0) ? qo : ko;
            #pragma unroll
            for (int t=0;t<2;++t) {
                int c = tid + t*256;
                int n2 = c>>3, blk = c&7;
                int o_in = o0 + blk*8 - part*192;
                int head = o_in>>5, d = o_in&31;
                *(int4*)(dst + (((size_t)b_*6+head)*64 + n2)*32 + d) =
                    *(const int4*)(T + n2*72 + blk*8);
            }
        } else {
            #pragma unroll
            for (int j=0;j<4;++j)
                #pragma unroll
                for (int rg=0;rg<4;++rg) {
                    int n2 = wv*16 + quad*4 + rg;
                    T[(j*16+lrow)*72 + n2] = f2bf(acc[j][rg]+bv[j]);
                }
            __syncthreads();
            #pragma unroll
            for (int t=0;t<2;++t) {
                int c = tid + t*256;
                int ol = c>>3, nb = (c&7)*8;
                int o_in = o0 + ol - 384;
                int head = o_in>>5, d = o_in&31;
                *(int4*)(vo + (((size_t)b_*6+head)*32 + d)*64 + nb) =
                    *(const int4*)(T + ol*72 + nb);
            }
        }
    }
}

// ---------------- windowed attention: 1 block/window, 6 waves = 6 heads ----------------
__global__ __launch_bounds__(384) void attn_kernel(
    const unsigned short* __restrict__ q, const unsigned short* __restrict__ k,
    const unsigned short* __restrict__ vT, const float* __restrict__ rpb,
    unsigned short* __restrict__ ao)
{
    __shared__ float rpb_s[1350];
    __shared__ __attribute__((aligned(16))) unsigned short p_lds[6*4608];
    const int b_ = blockIdx.x;
    const int h = threadIdx.x >> 6;
    const int lane = threadIdx.x & 63, lrow = lane & 15, quad = lane >> 4;
    for (int i = threadIdx.x; i < 1350; i += 384) rpb_s[i] = rpb[i];
    __syncthreads();

    const size_t hb = ((size_t)b_*6 + h)*2048;
    const unsigned short* qb = q  + hb;
    const unsigned short* kb = k  + hb;
    const unsigned short* vb = vT + hb;

    s16x8 qf[4], kf[4];
    #pragma unroll
    for (int i = 0; i < 4; ++i) qf[i] = *(const s16x8*)(qb + (i*16+lrow)*32 + quad*8);
    #pragma unroll
    for (int j = 0; j < 4; ++j) kf[j] = *(const s16x8*)(kb + (j*16+lrow)*32 + quad*8);

    const f32x4 zz = {0.f,0.f,0.f,0.f};
    f32x4 s[4][4];
    #pragma unroll
    for (int i = 0; i < 4; ++i)
        #pragma unroll
        for (int j = 0; j < 4; ++j)
            s[i][j] = __builtin_amdgcn_mfma_f32_16x16x32_bf16(qf[i], kf[j], zz, 0, 0, 0);

    const int wi = b_ & 255, wh = wi >> 4, ww = wi & 15;
    int labm[4];
    #pragma unroll
    for (int j = 0; j < 4; ++j) {
        int m = j*16 + lrow;
        labm[j] = flab(wh*8 + (m >> 3))*3 + flab(ww*8 + (m & 7));
    }
    unsigned short* pl = p_lds + h*4608;
    #pragma unroll
    for (int i = 0; i < 4; ++i) {
        #pragma unroll
        for (int rg = 0; rg < 4; ++rg) {
            int n = i*16 + quad*4 + rg;
            int rn = n >> 3, cn = n & 7;
            int labn = flab(wh*8 + rn)*3 + flab(ww*8 + cn);
            float vals[4];
            float vmax = -1e30f;
            #pragma unroll
            for (int j = 0; j < 4; ++j) {
                int m = j*16 + lrow;
                int idx = ((rn - (m >> 3) + 7)*15 + (cn - (m & 7) + 7))*6 + h;
                float val = s[i][j][rg] + rpb_s[idx];
                if (labn != labm[j]) val -= 100.f;
                vals[j] = val;
                vmax = fmaxf(vmax, val);
            }
            #pragma unroll
            for (int o = 1; o < 16; o <<= 1) vmax = fmaxf(vmax, __shfl_xor(vmax, o));
            float sum = 0.f;
            #pragma unroll
            for (int j = 0; j < 4; ++j) { vals[j] = __expf(vals[j] - vmax); sum += vals[j]; }
            #pragma unroll
            for (int o = 1; o < 16; o <<= 1) sum += __shfl_xor(sum, o);
            float inv = 1.f / sum;
            #pragma unroll
            for (int j = 0; j < 4; ++j) pl[n*72 + j*16 + lrow] = f2bf(vals[j]*inv);
        }
    }
    __syncthreads();

    f32x4 oacc[4][2];
    #pragma unroll
    for (int i = 0; i < 4; ++i) { oacc[i][0] = zz; oacc[i][1] = zz; }
    #pragma unroll
    for (int kc = 0; kc < 2; ++kc) {
        s16x8 vf[2];
        #pragma unroll
        for (int jd = 0; jd < 2; ++jd)
            vf[jd] = *(const s16x8*)(vb + (jd*16+lrow)*64 + kc*32 + quad*8);
        #pragma unroll
        for (int i = 0; i < 4; ++i) {
            s16x8 pf = *(const s16x8*)(pl + (i*16+lrow)*72 + kc*32 + quad*8);
            #pragma unroll
            for (int jd = 0; jd < 2; ++jd)
                oacc[i][jd] = __builtin_amdgcn_mfma_f32_16x16x32_bf16(pf, vf[jd], oacc[i][jd], 0, 0, 0);
        }
    }
    unsigned short* ob = ao + (size_t)b_*12288 + h*32;
    #pragma unroll
    for (int i = 0; i < 4; ++i)
        #pragma unroll
        for (int jd = 0; jd < 2; ++jd)
            #pragma unroll
            for (int rg = 0; rg < 4; ++rg) {
                int n = i*16 + quad*4 + rg;
                ob[(size_t)n*192 + jd*16 + lrow] = f2bf(oacc[i][jd][rg]);
            }
}

// =====================================================================
// 64x192 pipelined GEMM mainloop for projln: async16 + swizzle + 2-buffer.
// =====================================================================
__device__ __forceinline__ void mm64x192(
    const unsigned short* __restrict__ A, const unsigned short* __restrict__ W,
    size_t m0, unsigned short* As, unsigned short* Bs, f32x4 (&acc)[12])
{
    const int tid = threadIdx.x, wv = tid>>6, lane = tid&63;
    const int lrow = lane&15, quad = lane>>4;
    const int grow = lane>>2;                       // row within 16-row group
    const int gcb  = (lane&3) ^ ((lane>>3)&3);      // inverse-swizzled src col-block
    #pragma unroll
    for (int j=0;j<12;++j) acc[j] = (f32x4){0.f,0.f,0.f,0.f};

    const unsigned short* Ab = A + (m0 + grow)*192 + gcb*8;
    const unsigned short* Wb = W + (size_t)grow*192 + gcb*8;

    auto issue = [&](int k0, unsigned short* Ad, unsigned short* Bd) {
        async16(Ab + (size_t)(wv*16)*192 + k0,     Ad + wv*512);     // A: 4 groups
        async16(Wb + (size_t)(wv*16)*192 + k0,     Bd + wv*512);     // B: 12 groups
        async16(Wb + (size_t)((wv+4)*16)*192 + k0, Bd + (wv+4)*512);
        async16(Wb + (size_t)((wv+8)*16)*192 + k0, Bd + (wv+8)*512);
    };
    issue(0, As, Bs);
    int cur = 0;
    for (int k0=0; k0<192; k0+=32) {
        __syncthreads();                       // tile cur landed; prev reads done
        if (k0+32 < 192) issue(k0+32, As + (cur^1)*2048, Bs + (cur^1)*6144);
        const unsigned short* Ac = As + cur*2048;
        const unsigned short* Bc = Bs + cur*6144;
        const int rs = (quad ^ ((lrow>>1)&3)) << 3;
        s16x8 af = *(const s16x8*)(Ac + (wv*16+lrow)*32 + rs);
        #pragma unroll
        for (int j=0;j<12;++j) {
            s16x8 bf = *(const s16x8*)(Bc + (j*16+lrow)*32 + rs);
            acc[j] = __builtin_amdgcn_mfma_f32_16x16x32_bf16(af, bf, acc[j], 0, 0, 0);
        }
        cur ^= 1;
    }
}

// =====================================================================
// proj GEMM (full O=192) + window-reverse/roll + residual + LN2, fused.
// Writes x1 fp32 (token layout) + xln2 in BLOCKED layout:
// xln2[mt][ks][128][32] pre-swizzled; m-tile stride 24576 shorts.
// =====================================================================
__global__ __launch_bounds__(256) void projln_kernel(
    const unsigned short* __restrict__ A, const unsigned short* __restrict__ W,
    const float* __restrict__ pbias, const float* __restrict__ x,
    const float* __restrict__ g2, const float* __restrict__ b2,
    float* __restrict__ x1, unsigned short* __restrict__ xln2b)
{
    __shared__ __attribute__((aligned(16))) char smem[32768];
    unsigned short* As = (unsigned short*)smem;             // 2 x 4KB
    unsigned short* Bs = (unsigned short*)(smem + 8192);    // 2 x 12KB
    const int b_ = blockIdx.x;
    const int tid = threadIdx.x, wv = tid>>6, lane = tid&63;
    const int lrow = lane&15, quad = lane>>4;
    const size_t m0 = (size_t)b_*64;

    f32x4 acc[12];
    mm64x192(A, W, m0, As, Bs, acc);
    __syncthreads();

    const int bb = b_>>8, wi = b_&255, wh = wi>>4, ww = wi&15;
    float bv[12], gv[12], b2v[12];
    #pragma unroll
    for (int j=0;j<12;++j) {
        bv[j]  = pbias[j*16+lrow];
        gv[j]  = g2[j*16+lrow];
        b2v[j] = b2[j*16+lrow];
    }
    unsigned short* T = (unsigned short*)smem;   // 64x200 (25.6KB <= 32KB)
    #pragma unroll
    for (int rg=0;rg<4;++rg) {
        int n2 = wv*16 + quad*4 + rg;
        int r = n2>>3, c = n2&7;
        int hh = (wh*8+r+4)&127, wp = (ww*8+c+4)&127;   // roll(+4) back
        size_t tok = ((size_t)bb*128+hh)*128 + wp;
        float xv[12];
        float s = 0.f;
        #pragma unroll
        for (int j=0;j<12;++j) {
            float t = acc[j][rg] + bv[j] + x[tok*192 + j*16 + lrow];
            xv[j] = t; s += t;
        }
        #pragma unroll
        for (int o=1;o<16;o<<=1) s += __shfl_xor(s, o);
        float mu = s*(1.0f/192.0f);
        float qv = 0.f;
        #pragma unroll
        for (int j=0;j<12;++j){ float d = xv[j]-mu; qv += d*d; }
        #pragma unroll
        for (int o=1;o<16;o<<=1) qv += __shfl_xor(qv, o);
        float rstd = rsqrtf(qv*(1.0f/192.0f) + 1e-5f);
        #pragma unroll
        for (int j=0;j<12;++j) {
            x1[tok*192 + j*16 + lrow] = xv[j];
            T[n2*200 + j*16 + lrow] = f2bf((xv[j]-mu)*rstd*gv[j] + b2v[j]);
        }
    }
    __syncthreads();
    #pragma unroll
    for (int t=0;t<6;++t) {
        int cid = tid + t*256;                   // 0..1535
        int n2 = cid/24, blk = cid%24;
        int r = n2>>3, c = n2&7;
        int hh = (wh*8+r+4)&127, wp = (ww*8+c+4)&127;
        size_t tok = ((size_t)bb*128+hh)*128 + wp;
        int row = (int)(tok & 127);
        int ks = blk>>2, kb = blk&3;
        int sw = (kb ^ ((row>>1)&3)) << 3;
        *(int4*)(xln2b + (tok>>7)*24576 + ks*4096 + row*32 + sw) =
            *(const int4*)(T + n2*200 + blk*8);
    }
}

// =====================================================================
// FUSED MLP v4: producer-consumer wave specialization.
// 512 threads = 8 waves: waves 0-3 = fc1 producers (64 rows x 48 h-cols
// each per chunk, +GELU), waves 4-7 = fc2 consumers (64 rows x 48 out-
// cols each, accumulate over all 4 chunks). Hld double-buffered: phase
// ph runs fc1(chunk ph) CONCURRENTLY with fc2(chunk ph-1). 6 barriers
// (vs 9), block critical path ~ 5*max(fc1,fc2) vs 4*(fc1+GELU+fc2).
// acc[4][3] is role-shared (fc1 re-zeros per phase; fc2 persists) to
// keep the register union ~105 VGPR (4 waves/SIMD). LDS 24+48=72KB.
// =====================================================================
__global__ __launch_bounds__(512, 4) void mlp_kernel(
    const unsigned short* __restrict__ Ablk,   // xln2b [1024][6][128][32] swizzled
    const unsigned short* __restrict__ W1b,    // [4][6][192][32]
    const float* __restrict__ fc1b,
    const unsigned short* __restrict__ W2b,    // [4][24][48][32]
    const float* __restrict__ fc2b,
    const float* __restrict__ x1, float* __restrict__ out)
{
    __shared__ __attribute__((aligned(16))) unsigned short Ald[6*2048];     // 24KB
    __shared__ __attribute__((aligned(16))) unsigned short Hld[2*6*2048];   // 48KB
    const int b_ = blockIdx.x;
    const int mt = b_>>1, half = b_&1;
    const int tid = threadIdx.x, wv = tid>>6, lane = tid&63;
    const int lrow = lane&15, quad = lane>>4;
    const bool fc1w = (wv < 4);
    const int w4 = wv & 3;
    const int c0 = w4*48;
    const int rs = (quad ^ ((lrow>>1)&3)) << 3;   // swizzled col-block (shorts)

    // ---- stage A: 64 rows x 192 = 24 chunks x 1KB, linear async16 ----
    {
        const unsigned short* src = Ablk + (size_t)mt*24576 + half*2048 + lane*8;
        #pragma unroll
        for (int r=0;r<3;++r) {
            int c = r*8 + wv;                      // chunk 0..23: ks=c>>2, q=c&3
            async16(src + (c>>2)*4096 + (c&3)*512, Ald + c*512);
        }
    }

    // role-shared accumulator: fc1 re-zeros per phase; fc2 persists.
    f32x4 acc[4][3];
    #pragma unroll
    for (int i=0;i<4;++i)
        #pragma unroll
        for (int j=0;j<3;++j) acc[i][j] = (f32x4){0.f,0.f,0.f,0.f};

    const unsigned short* w1base = W1b + (size_t)c0*32 + quad*8;
    const unsigned short* w2base = W2b + (size_t)(w4*24)*1536 + quad*8;
    // role-shared weight fragment registers, primed for chunk 0
    s16x8 bc[3];
    #pragma unroll
    for (int j=0;j<3;++j)
        bc[j] = fc1w ? *(const s16x8*)(w1base + (j*16+lrow)*32)
                     : *(const s16x8*)(w2base + (j*16+lrow)*32);

    __syncthreads();                               // A landed

    for (int ph = 0; ph < 5; ++ph) {
        if (fc1w) {
            if (ph < 4) {
                const int oc = ph;
                float bv[3];
                #pragma unroll
                for (int j=0;j<3;++j) bv[j] = fc1b[oc*192 + c0 + j*16 + lrow];
                #pragma unroll
                for (int i=0;i<4;++i)
                    #pragma unroll
                    for (int j=0;j<3;++j) acc[i][j] = (f32x4){0.f,0.f,0.f,0.f};
                const unsigned short* w1p = w1base + (size_t)(oc*6)*6144;
                #pragma unroll
                for (int ks=0;ks<6;++ks) {
                    s16x8 bn[3];
                    if (ks < 5) {
                        #pragma unroll
                        for (int j=0;j<3;++j)
                            bn[j] = *(const s16x8*)(w1p + (size_t)(ks+1)*6144 + (j*16 + lrow)*32);
                    }
                    s16x8 af[4];
                    #pragma unroll
                    for (int i=0;i<4;++i)
                        af[i] = *(const s16x8*)(Ald + ks*2048 + (i*16 + lrow)*32 + rs);
                    #pragma unroll
                    for (int i=0;i<4;++i)
                        #pragma unroll
                        for (int j=0;j<3;++j)
                            acc[i][j] = __builtin_amdgcn_mfma_f32_16x16x32_bf16(af[i], bc[j], acc[i][j], 0, 0, 0);
                    if (ks < 5) { bc[0]=bn[0]; bc[1]=bn[1]; bc[2]=bn[2]; }
                }
                // prefetch next chunk's first fragments (lands under GELU)
                if (oc < 3) {
                    #pragma unroll
                    for (int j=0;j<3;++j)
                        bc[j] = *(const s16x8*)(w1base + (size_t)((oc+1)*6)*6144 + (j*16 + lrow)*32);
                }
                // bias + tanh-GELU -> Hld[ph&1] ([6][64][32] swizzled)
                unsigned short* Hb = Hld + (ph&1)*12288;
                #pragma unroll
                for (int i=0;i<4;++i)
                    #pragma unroll
                    for (int j=0;j<3;++j)
                        #pragma unroll
                        for (int rg=0;rg<4;++rg) {
                            int row = i*16 + quad*4 + rg;
                            int o = c0 + j*16 + lrow;      // 0..191 within chunk
                            float v = acc[i][j][rg] + bv[j];
                            float v2 = v*v;
                            float z = v*(1.5957691216057308f + 0.07135481627f*v2);
                            float r = v * __builtin_amdgcn_rcpf(1.f + __expf(-z));
                            int ksh = o>>5, c5 = o&31;
                            Hb[ksh*2048 + row*32 + (((c5>>3) ^ ((row>>1)&3))<<3) + (c5&7)] = f2bf(r);
                        }
            }
        } else {
            if (ph >= 1) {
                const int oc = ph - 1;
                const unsigned short* Hb = Hld + (oc&1)*12288;
                const unsigned short* w2p = w2base + (size_t)(oc*6)*1536;
                #pragma unroll
                for (int ksl=0;ksl<6;++ksl) {
                    s16x8 bn[3];
                    if (ksl < 5) {
                        #pragma unroll
                        for (int j=0;j<3;++j)
                            bn[j] = *(const s16x8*)(w2p + (size_t)(ksl+1)*1536 + (j*16 + lrow)*32);
                    }
                    s16x8 af[4];
                    #pragma unroll
                    for (int i=0;i<4;++i)
                        af[i] = *(const s16x8*)(Hb + ksl*2048 + (i*16 + lrow)*32 + rs);
                    #pragma unroll
                    for (int i=0;i<4;++i)
                        #pragma unroll
                        for (int j=0;j<3;++j)
                            acc[i][j] = __builtin_amdgcn_mfma_f32_16x16x32_bf16(af[i], bc[j], acc[i][j], 0, 0, 0);
                    if (ksl < 5) { bc[0]=bn[0]; bc[1]=bn[1]; bc[2]=bn[2]; }
                }
                // prefetch next chunk's first fragments (lands across barrier)
                if (oc < 3) {
                    #pragma unroll
                    for (int j=0;j<3;++j)
                        bc[j] = *(const s16x8*)(w2base + (size_t)((oc+1)*6)*1536 + (j*16 + lrow)*32);
                }
            }
        }
        __syncthreads();
    }

    // ---- bias + residual -> out (fc2 waves own the output) ----
    if (!fc1w) {
        float bv2[3];
        #pragma unroll
        for (int j=0;j<3;++j) bv2[j] = fc2b[c0 + j*16 + lrow];
        #pragma unroll
        for (int i=0;i<4;++i)
            #pragma unroll
            for (int j=0;j<3;++j)
                #pragma unroll
                for (int rg=0;rg<4;++rg) {
                    size_t grow = (size_t)mt*128 + half*64 + i*16 + quad*4 + rg;
                    size_t ad = grow*192 + c0 + j*16 + lrow;
                    out[ad] = acc[i][j][rg] + bv2[j] + x1[ad];
                }
    }
}

extern "C" void kernel_launch(void* const* d_in, const int* in_sizes, int n_in,
                              void* d_out, int out_size, void* d_ws, size_t ws_size,
                              hipStream_t stream)
{
    const float* x      = (const float*)d_in[0];
    const float* g1     = (const float*)d_in[1];
    const float* b1     = (const float*)d_in[2];
    const float* qkv_w  = (const float*)d_in[3];
    const float* qkv_b  = (const float*)d_in[4];
    const float* rpb    = (const float*)d_in[5];
    const float* proj_w = (const float*)d_in[6];
    const float* proj_b = (const float*)d_in[7];
    const float* g2     = (const float*)d_in[8];
    const float* b2     = (const float*)d_in[9];
    const float* fc1_w  = (const float*)d_in[10];
    const float* fc1_b  = (const float*)d_in[11];
    const float* fc2_w  = (const float*)d_in[12];
    const float* fc2_b  = (const float*)d_in[13];
    float* out = (float*)d_out;
    char* ws = (char*)d_ws;

    if (ws_size < 353206272ULL) return;

    unsigned short* qbuf  = (unsigned short*)(ws + 0);          // 50.3MB
    unsigned short* kbuf  = (unsigned short*)(ws + 50331648);   // 50.3MB
    unsigned short* vbuf  = (unsigned short*)(ws + 100663296);  // 50.3MB (vT)
    unsigned short* attnO = (unsigned short*)(ws + 150994944);  // 50.3MB
    float*          x1    = (float*)        (ws + 201326592);   // 100.7MB
    unsigned short* xln2  = (unsigned short*)(ws + 301989888);  // 50.3MB (blocked, 1024x24576)
    unsigned short* wq    = (unsigned short*)(ws + 352321536);
    unsigned short* wp    = (unsigned short*)(ws + 352321536 + 221184);
    unsigned short* w1b   = (unsigned short*)(ws + 352321536 + 221184 + 73728);
    unsigned short* w2b   = (unsigned short*)(ws + 352321536 + 221184 + 73728 + 294912);

    wconv_all<<<576, 256, 0, stream>>>(qkv_w, proj_w, fc1_w, fc2_w, wq, wp, w1b, w2b);
    lnqkv_kernel<<<2048, 256, 0, stream>>>(x, g1, b1, wq, qkv_b, qbuf, kbuf, vbuf);
    attn_kernel<<<2048, 384, 0, stream>>>(qbuf, kbuf, vbuf, rpb, attnO);
    projln_kernel<<<2048, 256, 0, stream>>>(attnO, wp, proj_b, x, g2, b2, x1, xln2);
    mlp_kernel<<<2048, 512, 0, stream>>>(xln2, w1b, fc1_b, w2b, fc2_b, x1, out);
}

// Round 13
// 646.995 us; speedup vs baseline: 1.0273x; 1.0273x over previous
//
#include <hip/hip_runtime.h>
#include <hip/hip_bf16.h>

typedef __attribute__((ext_vector_type(8))) short s16x8;
typedef __attribute__((ext_vector_type(4))) float f32x4;

__device__ __forceinline__ unsigned short f2bf(float f){
    __hip_bfloat16 h = __float2bfloat16(f);
    return *reinterpret_cast<unsigned short*>(&h);
}

__device__ __forceinline__ int flab(int g){ return (g < 120) ? 0 : ((g < 124) ? 1 : 2); }

// async global->LDS, 16B per lane; LDS dest = wave-uniform base + lane*16
__device__ __forceinline__ void async16(const void* g, void* l){
    __builtin_amdgcn_global_load_lds(
        (const __attribute__((address_space(1))) unsigned int*)g,
        (__attribute__((address_space(3))) unsigned int*)l, 16, 0, 0);
}

// ---------------- weight fp32 -> bf16 (w1/w2 into blocked layouts) --------
// w1b[oc 0..3][ks 0..5][192][32]  (fc1_w 768x192; oc = 192-row chunk)
// w2b[q 0..3][ks 0..23][48][32]   (fc2_w 192x768)
__global__ __launch_bounds__(256) void wconv_all(
    const float* __restrict__ w0, const float* __restrict__ w1,
    const float* __restrict__ w2, const float* __restrict__ w3,
    unsigned short* __restrict__ o0, unsigned short* __restrict__ o1,
    unsigned short* __restrict__ o2, unsigned short* __restrict__ o3)
{
    int i = blockIdx.x*256 + threadIdx.x;
    if (i < 110592) o0[i] = f2bf(w0[i]);   // qkv_w 576x192
    if (i < 36864)  o1[i] = f2bf(w1[i]);   // proj_w 192x192
    if (i < 147456) {
        int o = i/192, k = i - o*192;
        int oc = o/192, r = o - oc*192, ks = k>>5, c = k&31;
        o2[((oc*6 + ks)*192 + r)*32 + c] = f2bf(w2[i]);
    }
    if (i < 147456) {
        int o = i/768, k = i - o*768;
        int q = o/48, r = o - q*48, ks = k>>5, c = k&31;
        o3[((q*24 + ks)*48 + r)*32 + c] = f2bf(w3[i]);
    }
}

// =====================================================================
// LN1 + shift + window partition + QKV GEMM, fused. One block per window.
// =====================================================================
__global__ __launch_bounds__(256) void lnqkv_kernel(
    const float* __restrict__ x, const float* __restrict__ g1, const float* __restrict__ b1,
    const unsigned short* __restrict__ wq, const float* __restrict__ qkvb,
    unsigned short* __restrict__ qo, unsigned short* __restrict__ ko,
    unsigned short* __restrict__ vo)
{
    __shared__ __attribute__((aligned(16))) unsigned short win[64*200];  // 25.6KB
    __shared__ __attribute__((aligned(16))) unsigned short Bs[64*200];   // 25.6KB (B-tile / T)
    const int b_ = blockIdx.x;
    const int bb = b_>>8, wi = b_&255, wh = wi>>4, ww = wi&15;
    const int tid = threadIdx.x;
    const int wv = tid>>6, lane = tid&63, lrow = lane&15, quad = lane>>4;

    // ---- LN1: thread t -> token n = t>>2, quarter q4 = t&3 (48 ch each) ----
    {
        const int n = tid>>2, q4 = tid&3;
        const int r = n>>3, c = n&7;
        const int hh = (wh*8 + r + 4)&127, wp = (ww*8 + c + 4)&127;  // roll(-4)
        const float* px = x + (((size_t)bb*128+hh)*128+wp)*192 + q4*48;
        float v[48];
        #pragma unroll
        for (int m=0;m<12;++m) *(float4*)(v+m*4) = *(const float4*)(px+m*4);
        float s = 0.f;
        #pragma unroll
        for (int k=0;k<48;++k) s += v[k];
        s += __shfl_xor(s,1); s += __shfl_xor(s,2);
        float mu = s*(1.0f/192.0f);
        float qv = 0.f;
        #pragma unroll
        for (int k=0;k<48;++k){ float d=v[k]-mu; qv += d*d; }
        qv += __shfl_xor(qv,1); qv += __shfl_xor(qv,2);
        float rstd = rsqrtf(qv*(1.0f/192.0f) + 1e-5f);
        const float* pg = g1 + q4*48;
        const float* pb = b1 + q4*48;
        unsigned short* pw = win + n*200 + q4*48;
        #pragma unroll
        for (int k=0;k<48;++k) pw[k] = f2bf((v[k]-mu)*rstd*pg[k] + pb[k]);
    }
    __syncthreads();

    // hoist A fragments (reused by every o-tile)
    s16x8 af[6];
    #pragma unroll
    for (int kc=0;kc<6;++kc)
        af[kc] = *(const s16x8*)(win + (wv*16+lrow)*200 + kc*32 + quad*8);

    for (int ot=0; ot<9; ++ot) {
        const int o0 = ot*64;
        __syncthreads();                       // Bs free (prev T reads done)
        #pragma unroll
        for (int t=0;t<6;++t) {
            int cid = tid + t*256;             // 0..1535, globally contiguous
            *(int4*)(Bs + (cid/24)*200 + (cid%24)*8) =
                *(const int4*)(wq + (size_t)o0*192 + cid*8);
        }
        __syncthreads();
        f32x4 acc[4];
        #pragma unroll
        for (int j=0;j<4;++j) acc[j] = (f32x4){0.f,0.f,0.f,0.f};
        #pragma unroll
        for (int kc=0;kc<6;++kc)
            #pragma unroll
            for (int j=0;j<4;++j) {
                s16x8 bf = *(const s16x8*)(Bs + (j*16+lrow)*200 + kc*32 + quad*8);
                acc[j] = __builtin_amdgcn_mfma_f32_16x16x32_bf16(af[kc], bf, acc[j], 0, 0, 0);
            }
        __syncthreads();                       // done reading Bs; reuse as T
        unsigned short* T = Bs;
        const int part = ot/3;                 // 0=q 1=k 2=v
        float bv[4];
        #pragma unroll
        for (int j=0;j<4;++j) bv[j] = qkvb[o0 + j*16 + lrow];

        if (part < 2) {
            const float scale = (part==0) ? 0.17677669529663687f : 1.0f;
            #pragma unroll
            for (int j=0;j<4;++j)
                #pragma unroll
                for (int rg=0;rg<4;++rg) {
                    int n2 = wv*16 + quad*4 + rg;
                    T[n2*72 + j*16 + lrow] = f2bf((acc[j][rg]+bv[j])*scale);
                }
            __syncthreads();
            unsigned short* dst = (part==0) ? qo : ko;
            #pragma unroll
            for (int t=0;t<2;++t) {
                int c = tid + t*256;
                int n2 = c>>3, blk = c&7;
                int o_in = o0 + blk*8 - part*192;
                int head = o_in>>5, d = o_in&31;
                *(int4*)(dst + (((size_t)b_*6+head)*64 + n2)*32 + d) =
                    *(const int4*)(T + n2*72 + blk*8);
            }
        } else {
            #pragma unroll
            for (int j=0;j<4;++j)
                #pragma unroll
                for (int rg=0;rg<4;++rg) {
                    int n2 = wv*16 + quad*4 + rg;
                    T[(j*16+lrow)*72 + n2] = f2bf(acc[j][rg]+bv[j]);
                }
            __syncthreads();
            #pragma unroll
            for (int t=0;t<2;++t) {
                int c = tid + t*256;
                int ol = c>>3, nb = (c&7)*8;
                int o_in = o0 + ol - 384;
                int head = o_in>>5, d = o_in&31;
                *(int4*)(vo + (((size_t)b_*6+head)*32 + d)*64 + nb) =
                    *(const int4*)(T + ol*72 + nb);
            }
        }
    }
}

// ---------------- windowed attention: 1 block/window, 6 waves = 6 heads ----------------
__global__ __launch_bounds__(384) void attn_kernel(
    const unsigned short* __restrict__ q, const unsigned short* __restrict__ k,
    const unsigned short* __restrict__ vT, const float* __restrict__ rpb,
    unsigned short* __restrict__ ao)
{
    __shared__ float rpb_s[1350];
    __shared__ __attribute__((aligned(16))) unsigned short p_lds[6*4608];
    const int b_ = blockIdx.x;
    const int h = threadIdx.x >> 6;
    const int lane = threadIdx.x & 63, lrow = lane & 15, quad = lane >> 4;
    for (int i = threadIdx.x; i < 1350; i += 384) rpb_s[i] = rpb[i];
    __syncthreads();

    const size_t hb = ((size_t)b_*6 + h)*2048;
    const unsigned short* qb = q  + hb;
    const unsigned short* kb = k  + hb;
    const unsigned short* vb = vT + hb;

    s16x8 qf[4], kf[4];
    #pragma unroll
    for (int i = 0; i < 4; ++i) qf[i] = *(const s16x8*)(qb + (i*16+lrow)*32 + quad*8);
    #pragma unroll
    for (int j = 0; j < 4; ++j) kf[j] = *(const s16x8*)(kb + (j*16+lrow)*32 + quad*8);

    const f32x4 zz = {0.f,0.f,0.f,0.f};
    f32x4 s[4][4];
    #pragma unroll
    for (int i = 0; i < 4; ++i)
        #pragma unroll
        for (int j = 0; j < 4; ++j)
            s[i][j] = __builtin_amdgcn_mfma_f32_16x16x32_bf16(qf[i], kf[j], zz, 0, 0, 0);

    const int wi = b_ & 255, wh = wi >> 4, ww = wi & 15;
    int labm[4];
    #pragma unroll
    for (int j = 0; j < 4; ++j) {
        int m = j*16 + lrow;
        labm[j] = flab(wh*8 + (m >> 3))*3 + flab(ww*8 + (m & 7));
    }
    unsigned short* pl = p_lds + h*4608;
    #pragma unroll
    for (int i = 0; i < 4; ++i) {
        #pragma unroll
        for (int rg = 0; rg < 4; ++rg) {
            int n = i*16 + quad*4 + rg;
            int rn = n >> 3, cn = n & 7;
            int labn = flab(wh*8 + rn)*3 + flab(ww*8 + cn);
            float vals[4];
            float vmax = -1e30f;
            #pragma unroll
            for (int j = 0; j < 4; ++j) {
                int m = j*16 + lrow;
                int idx = ((rn - (m >> 3) + 7)*15 + (cn - (m & 7) + 7))*6 + h;
                float val = s[i][j][rg] + rpb_s[idx];
                if (labn != labm[j]) val -= 100.f;
                vals[j] = val;
                vmax = fmaxf(vmax, val);
            }
            #pragma unroll
            for (int o = 1; o < 16; o <<= 1) vmax = fmaxf(vmax, __shfl_xor(vmax, o));
            float sum = 0.f;
            #pragma unroll
            for (int j = 0; j < 4; ++j) { vals[j] = __expf(vals[j] - vmax); sum += vals[j]; }
            #pragma unroll
            for (int o = 1; o < 16; o <<= 1) sum += __shfl_xor(sum, o);
            float inv = 1.f / sum;
            #pragma unroll
            for (int j = 0; j < 4; ++j) pl[n*72 + j*16 + lrow] = f2bf(vals[j]*inv);
        }
    }
    __syncthreads();

    f32x4 oacc[4][2];
    #pragma unroll
    for (int i = 0; i < 4; ++i) { oacc[i][0] = zz; oacc[i][1] = zz; }
    #pragma unroll
    for (int kc = 0; kc < 2; ++kc) {
        s16x8 vf[2];
        #pragma unroll
        for (int jd = 0; jd < 2; ++jd)
            vf[jd] = *(const s16x8*)(vb + (jd*16+lrow)*64 + kc*32 + quad*8);
        #pragma unroll
        for (int i = 0; i < 4; ++i) {
            s16x8 pf = *(const s16x8*)(pl + (i*16+lrow)*72 + kc*32 + quad*8);
            #pragma unroll
            for (int jd = 0; jd < 2; ++jd)
                oacc[i][jd] = __builtin_amdgcn_mfma_f32_16x16x32_bf16(pf, vf[jd], oacc[i][jd], 0, 0, 0);
        }
    }
    unsigned short* ob = ao + (size_t)b_*12288 + h*32;
    #pragma unroll
    for (int i = 0; i < 4; ++i)
        #pragma unroll
        for (int jd = 0; jd < 2; ++jd)
            #pragma unroll
            for (int rg = 0; rg < 4; ++rg) {
                int n = i*16 + quad*4 + rg;
                ob[(size_t)n*192 + jd*16 + lrow] = f2bf(oacc[i][jd][rg]);
            }
}

// =====================================================================
// 64x192 pipelined GEMM mainloop for projln: async16 + swizzle + 2-buffer.
// =====================================================================
__device__ __forceinline__ void mm64x192(
    const unsigned short* __restrict__ A, const unsigned short* __restrict__ W,
    size_t m0, unsigned short* As, unsigned short* Bs, f32x4 (&acc)[12])
{
    const int tid = threadIdx.x, wv = tid>>6, lane = tid&63;
    const int lrow = lane&15, quad = lane>>4;
    const int grow = lane>>2;                       // row within 16-row group
    const int gcb  = (lane&3) ^ ((lane>>3)&3);      // inverse-swizzled src col-block
    #pragma unroll
    for (int j=0;j<12;++j) acc[j] = (f32x4){0.f,0.f,0.f,0.f};

    const unsigned short* Ab = A + (m0 + grow)*192 + gcb*8;
    const unsigned short* Wb = W + (size_t)grow*192 + gcb*8;

    auto issue = [&](int k0, unsigned short* Ad, unsigned short* Bd) {
        async16(Ab + (size_t)(wv*16)*192 + k0,     Ad + wv*512);     // A: 4 groups
        async16(Wb + (size_t)(wv*16)*192 + k0,     Bd + wv*512);     // B: 12 groups
        async16(Wb + (size_t)((wv+4)*16)*192 + k0, Bd + (wv+4)*512);
        async16(Wb + (size_t)((wv+8)*16)*192 + k0, Bd + (wv+8)*512);
    };
    issue(0, As, Bs);
    int cur = 0;
    for (int k0=0; k0<192; k0+=32) {
        __syncthreads();                       // tile cur landed; prev reads done
        if (k0+32 < 192) issue(k0+32, As + (cur^1)*2048, Bs + (cur^1)*6144);
        const unsigned short* Ac = As + cur*2048;
        const unsigned short* Bc = Bs + cur*6144;
        const int rs = (quad ^ ((lrow>>1)&3)) << 3;
        s16x8 af = *(const s16x8*)(Ac + (wv*16+lrow)*32 + rs);
        #pragma unroll
        for (int j=0;j<12;++j) {
            s16x8 bf = *(const s16x8*)(Bc + (j*16+lrow)*32 + rs);
            acc[j] = __builtin_amdgcn_mfma_f32_16x16x32_bf16(af, bf, acc[j], 0, 0, 0);
        }
        cur ^= 1;
    }
}

// =====================================================================
// proj GEMM (full O=192) + window-reverse/roll + residual + LN2, fused.
// Writes x1 fp32 (token layout) + xln2 in BLOCKED layout:
// xln2[mt][ks][128][32] pre-swizzled; m-tile stride 24576 shorts.
// =====================================================================
__global__ __launch_bounds__(256) void projln_kernel(
    const unsigned short* __restrict__ A, const unsigned short* __restrict__ W,
    const float* __restrict__ pbias, const float* __restrict__ x,
    const float* __restrict__ g2, const float* __restrict__ b2,
    float* __restrict__ x1, unsigned short* __restrict__ xln2b)
{
    __shared__ __attribute__((aligned(16))) char smem[32768];
    unsigned short* As = (unsigned short*)smem;             // 2 x 4KB
    unsigned short* Bs = (unsigned short*)(smem + 8192);    // 2 x 12KB
    const int b_ = blockIdx.x;
    const int tid = threadIdx.x, wv = tid>>6, lane = tid&63;
    const int lrow = lane&15, quad = lane>>4;
    const size_t m0 = (size_t)b_*64;

    f32x4 acc[12];
    mm64x192(A, W, m0, As, Bs, acc);
    __syncthreads();

    const int bb = b_>>8, wi = b_&255, wh = wi>>4, ww = wi&15;
    float bv[12], gv[12], b2v[12];
    #pragma unroll
    for (int j=0;j<12;++j) {
        bv[j]  = pbias[j*16+lrow];
        gv[j]  = g2[j*16+lrow];
        b2v[j] = b2[j*16+lrow];
    }
    unsigned short* T = (unsigned short*)smem;   // 64x200 (25.6KB <= 32KB)
    #pragma unroll
    for (int rg=0;rg<4;++rg) {
        int n2 = wv*16 + quad*4 + rg;
        int r = n2>>3, c = n2&7;
        int hh = (wh*8+r+4)&127, wp = (ww*8+c+4)&127;   // roll(+4) back
        size_t tok = ((size_t)bb*128+hh)*128 + wp;
        float xv[12];
        float s = 0.f;
        #pragma unroll
        for (int j=0;j<12;++j) {
            float t = acc[j][rg] + bv[j] + x[tok*192 + j*16 + lrow];
            xv[j] = t; s += t;
        }
        #pragma unroll
        for (int o=1;o<16;o<<=1) s += __shfl_xor(s, o);
        float mu = s*(1.0f/192.0f);
        float qv = 0.f;
        #pragma unroll
        for (int j=0;j<12;++j){ float d = xv[j]-mu; qv += d*d; }
        #pragma unroll
        for (int o=1;o<16;o<<=1) qv += __shfl_xor(qv, o);
        float rstd = rsqrtf(qv*(1.0f/192.0f) + 1e-5f);
        #pragma unroll
        for (int j=0;j<12;++j) {
            x1[tok*192 + j*16 + lrow] = xv[j];
            T[n2*200 + j*16 + lrow] = f2bf((xv[j]-mu)*rstd*gv[j] + b2v[j]);
        }
    }
    __syncthreads();
    #pragma unroll
    for (int t=0;t<6;++t) {
        int cid = tid + t*256;                   // 0..1535
        int n2 = cid/24, blk = cid%24;
        int r = n2>>3, c = n2&7;
        int hh = (wh*8+r+4)&127, wp = (ww*8+c+4)&127;
        size_t tok = ((size_t)bb*128+hh)*128 + wp;
        int row = (int)(tok & 127);
        int ks = blk>>2, kb = blk&3;
        int sw = (kb ^ ((row>>1)&3)) << 3;
        *(int4*)(xln2b + (tok>>7)*24576 + ks*4096 + row*32 + sw) =
            *(const int4*)(T + n2*200 + blk*8);
    }
}

// =====================================================================
// FUSED MLP v5: v3's chunked structure at 32 rows/block for TLP.
// 256 threads = 4 waves; wave = 48-col quarter of both h-chunk and out.
// Per-wave tiles identical to v3 (fc1 a1[2][3] per chunk, fc2 a2[2][3]
// persistent, rolling weight prefetch). LDS: Ald 12KB + Hld 12KB = 24KB
// -> 6 blocks/CU (24 waves, vs v3's ~13). Grid 4096. h never hits HBM.
// (v4's role-shared-register specialization spilled to scratch: WRITE
// 98->287MB. No register sharing across divergent roles here.)
// =====================================================================
__global__ __launch_bounds__(256, 6) void mlp_kernel(
    const unsigned short* __restrict__ Ablk,   // xln2b [1024][6][128][32] swizzled
    const unsigned short* __restrict__ W1b,    // [4][6][192][32]
    const float* __restrict__ fc1b,
    const unsigned short* __restrict__ W2b,    // [4][24][48][32]
    const float* __restrict__ fc2b,
    const float* __restrict__ x1, float* __restrict__ out)
{
    __shared__ __attribute__((aligned(16))) unsigned short Ald[6*1024];   // 12KB
    __shared__ __attribute__((aligned(16))) unsigned short Hld[6*1024];   // 12KB
    const int b_ = blockIdx.x;
    const int mt = b_>>2, sub = b_&3;              // 32-row slice of the 128-row m-tile
    const int tid = threadIdx.x, wv = tid>>6, lane = tid&63;
    const int lrow = lane&15, quad = lane>>4;
    const int c0 = wv*48;
    const int rs = (quad ^ ((lrow>>1)&3)) << 3;    // swizzled col-block (shorts)

    // ---- stage A: 32 rows x 192 = 12 chunks x 1KB, linear async16 ----
    {
        const unsigned short* src = Ablk + (size_t)mt*24576 + sub*1024 + lane*8;
        #pragma unroll
        for (int r=0;r<3;++r) {
            int c = r*4 + wv;                      // chunk 0..11: ks=c>>1, half=c&1
            async16(src + (c>>1)*4096 + (c&1)*512, Ald + c*512);
        }
    }

    // fc1 bias (all 4 chunks upfront: 12 scalars, L2-hot)
    float bv1[4][3];
    #pragma unroll
    for (int oc=0;oc<4;++oc)
        #pragma unroll
        for (int j=0;j<3;++j) bv1[oc][j] = fc1b[oc*192 + c0 + j*16 + lrow];

    f32x4 a2[2][3];
    #pragma unroll
    for (int i=0;i<2;++i)
        #pragma unroll
        for (int j=0;j<3;++j) a2[i][j] = (f32x4){0.f,0.f,0.f,0.f};

    // rolling fc1 weight prefetch: first fragments of oc=0, ks=0
    const unsigned short* w1base = W1b + (size_t)c0*32 + quad*8;
    s16x8 b1c[3];
    #pragma unroll
    for (int j=0;j<3;++j) b1c[j] = *(const s16x8*)(w1base + (j*16 + lrow)*32);

    __syncthreads();                               // A landed

    for (int oc=0; oc<4; ++oc) {
        const unsigned short* w1p = w1base + (size_t)(oc*6)*6144;
        // ---- fc1 partial: 32 rows x h-cols oc*192+c0..+47, K=192 ----
        f32x4 a1[2][3];
        #pragma unroll
        for (int i=0;i<2;++i)
            #pragma unroll
            for (int j=0;j<3;++j) a1[i][j] = (f32x4){0.f,0.f,0.f,0.f};
        #pragma unroll
        for (int ks=0;ks<6;++ks) {
            s16x8 b1n[3];
            if (ks < 5) {
                #pragma unroll
                for (int j=0;j<3;++j)
                    b1n[j] = *(const s16x8*)(w1p + (size_t)(ks+1)*6144 + (j*16 + lrow)*32);
            }
            s16x8 af[2];
            #pragma unroll
            for (int i=0;i<2;++i)
                af[i] = *(const s16x8*)(Ald + ks*1024 + (i*16 + lrow)*32 + rs);
            #pragma unroll
            for (int i=0;i<2;++i)
                #pragma unroll
                for (int j=0;j<3;++j)
                    a1[i][j] = __builtin_amdgcn_mfma_f32_16x16x32_bf16(af[i], b1c[j], a1[i][j], 0, 0, 0);
            if (ks < 5) { b1c[0]=b1n[0]; b1c[1]=b1n[1]; b1c[2]=b1n[2]; }
        }

        // prefetch fc2's first fragments (independent of Hld; lands under GELU)
        const unsigned short* w2p = W2b + (size_t)(wv*24 + oc*6)*1536 + quad*8;
        s16x8 b2c[3];
        #pragma unroll
        for (int j=0;j<3;++j) b2c[j] = *(const s16x8*)(w2p + (j*16 + lrow)*32);
        // prefetch next oc's fc1 first fragments (lands under GELU + fc2)
        if (oc < 3) {
            #pragma unroll
            for (int j=0;j<3;++j)
                b1c[j] = *(const s16x8*)(w1base + (size_t)((oc+1)*6)*6144 + (j*16 + lrow)*32);
        }

        if (oc) __syncthreads();                   // prev fc2 done reading Hld

        // ---- bias + tanh-GELU -> Hld ([6][32][32] swizzled) ----
        #pragma unroll
        for (int i=0;i<2;++i)
            #pragma unroll
            for (int j=0;j<3;++j)
                #pragma unroll
                for (int rg=0;rg<4;++rg) {
                    int row = i*16 + quad*4 + rg;  // local row 0..31
                    int o = c0 + j*16 + lrow;      // 0..191 within chunk
                    float v = a1[i][j][rg] + bv1[oc][j];
                    float v2 = v*v;
                    float z = v*(1.5957691216057308f + 0.07135481627f*v2);
                    float r = v * __builtin_amdgcn_rcpf(1.f + __expf(-z));
                    int ksh = o>>5, c5 = o&31;
                    Hld[ksh*1024 + row*32 + (((c5>>3) ^ ((row>>1)&3))<<3) + (c5&7)] = f2bf(r);
                }
        __syncthreads();                           // H visible

        // ---- fc2 accumulate: K-slice oc*192..+191 from Hld ----
        #pragma unroll
        for (int ksl=0;ksl<6;++ksl) {
            s16x8 b2n[3];
            if (ksl < 5) {
                #pragma unroll
                for (int j=0;j<3;++j)
                    b2n[j] = *(const s16x8*)(w2p + (size_t)(ksl+1)*1536 + (j*16 + lrow)*32);
            }
            s16x8 af2[2];
            #pragma unroll
            for (int i=0;i<2;++i)
                af2[i] = *(const s16x8*)(Hld + ksl*1024 + (i*16 + lrow)*32 + rs);
            #pragma unroll
            for (int i=0;i<2;++i)
                #pragma unroll
                for (int j=0;j<3;++j)
                    a2[i][j] = __builtin_amdgcn_mfma_f32_16x16x32_bf16(af2[i], b2c[j], a2[i][j], 0, 0, 0);
            if (ksl < 5) { b2c[0]=b2n[0]; b2c[1]=b2n[1]; b2c[2]=b2n[2]; }
        }
    }

    // ---- bias + residual -> out ----
    {
        float bv2[3];
        #pragma unroll
        for (int j=0;j<3;++j) bv2[j] = fc2b[c0 + j*16 + lrow];
        #pragma unroll
        for (int i=0;i<2;++i)
            #pragma unroll
            for (int j=0;j<3;++j)
                #pragma unroll
                for (int rg=0;rg<4;++rg) {
                    size_t grow = (size_t)mt*128 + sub*32 + i*16 + quad*4 + rg;
                    size_t ad = grow*192 + c0 + j*16 + lrow;
                    out[ad] = a2[i][j][rg] + bv2[j] + x1[ad];
                }
    }
}

extern "C" void kernel_launch(void* const* d_in, const int* in_sizes, int n_in,
                              void* d_out, int out_size, void* d_ws, size_t ws_size,
                              hipStream_t stream)
{
    const float* x      = (const float*)d_in[0];
    const float* g1     = (const float*)d_in[1];
    const float* b1     = (const float*)d_in[2];
    const float* qkv_w  = (const float*)d_in[3];
    const float* qkv_b  = (const float*)d_in[4];
    const float* rpb    = (const float*)d_in[5];
    const float* proj_w = (const float*)d_in[6];
    const float* proj_b = (const float*)d_in[7];
    const float* g2     = (const float*)d_in[8];
    const float* b2     = (const float*)d_in[9];
    const float* fc1_w  = (const float*)d_in[10];
    const float* fc1_b  = (const float*)d_in[11];
    const float* fc2_w  = (const float*)d_in[12];
    const float* fc2_b  = (const float*)d_in[13];
    float* out = (float*)d_out;
    char* ws = (char*)d_ws;

    if (ws_size < 353206272ULL) return;

    unsigned short* qbuf  = (unsigned short*)(ws + 0);          // 50.3MB
    unsigned short* kbuf  = (unsigned short*)(ws + 50331648);   // 50.3MB
    unsigned short* vbuf  = (unsigned short*)(ws + 100663296);  // 50.3MB (vT)
    unsigned short* attnO = (unsigned short*)(ws + 150994944);  // 50.3MB
    float*          x1    = (float*)        (ws + 201326592);   // 100.7MB
    unsigned short* xln2  = (unsigned short*)(ws + 301989888);  // 50.3MB (blocked, 1024x24576)
    unsigned short* wq    = (unsigned short*)(ws + 352321536);
    unsigned short* wp    = (unsigned short*)(ws + 352321536 + 221184);
    unsigned short* w1b   = (unsigned short*)(ws + 352321536 + 221184 + 73728);
    unsigned short* w2b   = (unsigned short*)(ws + 352321536 + 221184 + 73728 + 294912);

    wconv_all<<<576, 256, 0, stream>>>(qkv_w, proj_w, fc1_w, fc2_w, wq, wp, w1b, w2b);
    lnqkv_kernel<<<2048, 256, 0, stream>>>(x, g1, b1, wq, qkv_b, qbuf, kbuf, vbuf);
    attn_kernel<<<2048, 384, 0, stream>>>(qbuf, kbuf, vbuf, rpb, attnO);
    projln_kernel<<<2048, 256, 0, stream>>>(attnO, wp, proj_b, x, g2, b2, x1, xln2);
    mlp_kernel<<<4096, 256, 0, stream>>>(xln2, w1b, fc1_b, w2b, fc2_b, x1, out);
}

// Round 14
// 539.589 us; speedup vs baseline: 1.2317x; 1.1991x over previous
//
#include <hip/hip_runtime.h>
#include <hip/hip_bf16.h>

typedef __attribute__((ext_vector_type(8))) short s16x8;
typedef __attribute__((ext_vector_type(4))) float f32x4;

__device__ __forceinline__ unsigned short f2bf(float f){
    __hip_bfloat16 h = __float2bfloat16(f);
    return *reinterpret_cast<unsigned short*>(&h);
}

__device__ __forceinline__ int flab(int g){ return (g < 120) ? 0 : ((g < 124) ? 1 : 2); }

// async global->LDS, 16B per lane; LDS dest = wave-uniform base + lane*16
__device__ __forceinline__ void async16(const void* g, void* l){
    __builtin_amdgcn_global_load_lds(
        (const __attribute__((address_space(1))) unsigned int*)g,
        (__attribute__((address_space(3))) unsigned int*)l, 16, 0, 0);
}

// ---------------- weight fp32 -> bf16 (w1/w2 into blocked layouts) --------
// w1b[oc 0..3][ks 0..5][192][32]  (fc1_w 768x192; oc = 192-row chunk)
// w2b[q 0..3][ks 0..23][48][32]   (fc2_w 192x768)
__global__ __launch_bounds__(256) void wconv_all(
    const float* __restrict__ w0, const float* __restrict__ w1,
    const float* __restrict__ w2, const float* __restrict__ w3,
    unsigned short* __restrict__ o0, unsigned short* __restrict__ o1,
    unsigned short* __restrict__ o2, unsigned short* __restrict__ o3)
{
    int i = blockIdx.x*256 + threadIdx.x;
    if (i < 110592) o0[i] = f2bf(w0[i]);   // qkv_w 576x192
    if (i < 36864)  o1[i] = f2bf(w1[i]);   // proj_w 192x192
    if (i < 147456) {
        int o = i/192, k = i - o*192;
        int oc = o/192, r = o - oc*192, ks = k>>5, c = k&31;
        o2[((oc*6 + ks)*192 + r)*32 + c] = f2bf(w2[i]);
    }
    if (i < 147456) {
        int o = i/768, k = i - o*768;
        int q = o/48, r = o - q*48, ks = k>>5, c = k&31;
        o3[((q*24 + ks)*48 + r)*32 + c] = f2bf(w3[i]);
    }
}

// =====================================================================
// LN1 + shift + window partition + QKV GEMM, fused. One block per window.
// =====================================================================
__global__ __launch_bounds__(256) void lnqkv_kernel(
    const float* __restrict__ x, const float* __restrict__ g1, const float* __restrict__ b1,
    const unsigned short* __restrict__ wq, const float* __restrict__ qkvb,
    unsigned short* __restrict__ qo, unsigned short* __restrict__ ko,
    unsigned short* __restrict__ vo)
{
    __shared__ __attribute__((aligned(16))) unsigned short win[64*200];  // 25.6KB
    __shared__ __attribute__((aligned(16))) unsigned short Bs[64*200];   // 25.6KB (B-tile / T)
    const int b_ = blockIdx.x;
    const int bb = b_>>8, wi = b_&255, wh = wi>>4, ww = wi&15;
    const int tid = threadIdx.x;
    const int wv = tid>>6, lane = tid&63, lrow = lane&15, quad = lane>>4;

    // ---- LN1: thread t -> token n = t>>2, quarter q4 = t&3 (48 ch each) ----
    {
        const int n = tid>>2, q4 = tid&3;
        const int r = n>>3, c = n&7;
        const int hh = (wh*8 + r + 4)&127, wp = (ww*8 + c + 4)&127;  // roll(-4)
        const float* px = x + (((size_t)bb*128+hh)*128+wp)*192 + q4*48;
        float v[48];
        #pragma unroll
        for (int m=0;m<12;++m) *(float4*)(v+m*4) = *(const float4*)(px+m*4);
        float s = 0.f;
        #pragma unroll
        for (int k=0;k<48;++k) s += v[k];
        s += __shfl_xor(s,1); s += __shfl_xor(s,2);
        float mu = s*(1.0f/192.0f);
        float qv = 0.f;
        #pragma unroll
        for (int k=0;k<48;++k){ float d=v[k]-mu; qv += d*d; }
        qv += __shfl_xor(qv,1); qv += __shfl_xor(qv,2);
        float rstd = rsqrtf(qv*(1.0f/192.0f) + 1e-5f);
        const float* pg = g1 + q4*48;
        const float* pb = b1 + q4*48;
        unsigned short* pw = win + n*200 + q4*48;
        #pragma unroll
        for (int k=0;k<48;++k) pw[k] = f2bf((v[k]-mu)*rstd*pg[k] + pb[k]);
    }
    __syncthreads();

    // hoist A fragments (reused by every o-tile)
    s16x8 af[6];
    #pragma unroll
    for (int kc=0;kc<6;++kc)
        af[kc] = *(const s16x8*)(win + (wv*16+lrow)*200 + kc*32 + quad*8);

    for (int ot=0; ot<9; ++ot) {
        const int o0 = ot*64;
        __syncthreads();                       // Bs free (prev T reads done)
        #pragma unroll
        for (int t=0;t<6;++t) {
            int cid = tid + t*256;             // 0..1535, globally contiguous
            *(int4*)(Bs + (cid/24)*200 + (cid%24)*8) =
                *(const int4*)(wq + (size_t)o0*192 + cid*8);
        }
        __syncthreads();
        f32x4 acc[4];
        #pragma unroll
        for (int j=0;j<4;++j) acc[j] = (f32x4){0.f,0.f,0.f,0.f};
        #pragma unroll
        for (int kc=0;kc<6;++kc)
            #pragma unroll
            for (int j=0;j<4;++j) {
                s16x8 bf = *(const s16x8*)(Bs + (j*16+lrow)*200 + kc*32 + quad*8);
                acc[j] = __builtin_amdgcn_mfma_f32_16x16x32_bf16(af[kc], bf, acc[j], 0, 0, 0);
            }
        __syncthreads();                       // done reading Bs; reuse as T
        unsigned short* T = Bs;
        const int part = ot/3;                 // 0=q 1=k 2=v
        float bv[4];
        #pragma unroll
        for (int j=0;j<4;++j) bv[j] = qkvb[o0 + j*16 + lrow];

        if (part < 2) {
            const float scale = (part==0) ? 0.17677669529663687f : 1.0f;
            #pragma unroll
            for (int j=0;j<4;++j)
                #pragma unroll
                for (int rg=0;rg<4;++rg) {
                    int n2 = wv*16 + quad*4 + rg;
                    T[n2*72 + j*16 + lrow] = f2bf((acc[j][rg]+bv[j])*scale);
                }
            __syncthreads();
            unsigned short* dst = (part==0) ? qo : ko;
            #pragma unroll
            for (int t=0;t<2;++t) {
                int c = tid + t*256;
                int n2 = c>>3, blk = c&7;
                int o_in = o0 + blk*8 - part*192;
                int head = o_in>>5, d = o_in&31;
                *(int4*)(dst + (((size_t)b_*6+head)*64 + n2)*32 + d) =
                    *(const int4*)(T + n2*72 + blk*8);
            }
        } else {
            #pragma unroll
            for (int j=0;j<4;++j)
                #pragma unroll
                for (int rg=0;rg<4;++rg) {
                    int n2 = wv*16 + quad*4 + rg;
                    T[(j*16+lrow)*72 + n2] = f2bf(acc[j][rg]+bv[j]);
                }
            __syncthreads();
            #pragma unroll
            for (int t=0;t<2;++t) {
                int c = tid + t*256;
                int ol = c>>3, nb = (c&7)*8;
                int o_in = o0 + ol - 384;
                int head = o_in>>5, d = o_in&31;
                *(int4*)(vo + (((size_t)b_*6+head)*32 + d)*64 + nb) =
                    *(const int4*)(T + ol*72 + nb);
            }
        }
    }
}

// ---------------- windowed attention: 1 block/window, 6 waves = 6 heads ----------------
__global__ __launch_bounds__(384) void attn_kernel(
    const unsigned short* __restrict__ q, const unsigned short* __restrict__ k,
    const unsigned short* __restrict__ vT, const float* __restrict__ rpb,
    unsigned short* __restrict__ ao)
{
    __shared__ float rpb_s[1350];
    __shared__ __attribute__((aligned(16))) unsigned short p_lds[6*4608];
    const int b_ = blockIdx.x;
    const int h = threadIdx.x >> 6;
    const int lane = threadIdx.x & 63, lrow = lane & 15, quad = lane >> 4;
    for (int i = threadIdx.x; i < 1350; i += 384) rpb_s[i] = rpb[i];
    __syncthreads();

    const size_t hb = ((size_t)b_*6 + h)*2048;
    const unsigned short* qb = q  + hb;
    const unsigned short* kb = k  + hb;
    const unsigned short* vb = vT + hb;

    s16x8 qf[4], kf[4];
    #pragma unroll
    for (int i = 0; i < 4; ++i) qf[i] = *(const s16x8*)(qb + (i*16+lrow)*32 + quad*8);
    #pragma unroll
    for (int j = 0; j < 4; ++j) kf[j] = *(const s16x8*)(kb + (j*16+lrow)*32 + quad*8);

    const f32x4 zz = {0.f,0.f,0.f,0.f};
    f32x4 s[4][4];
    #pragma unroll
    for (int i = 0; i < 4; ++i)
        #pragma unroll
        for (int j = 0; j < 4; ++j)
            s[i][j] = __builtin_amdgcn_mfma_f32_16x16x32_bf16(qf[i], kf[j], zz, 0, 0, 0);

    const int wi = b_ & 255, wh = wi >> 4, ww = wi & 15;
    int labm[4];
    #pragma unroll
    for (int j = 0; j < 4; ++j) {
        int m = j*16 + lrow;
        labm[j] = flab(wh*8 + (m >> 3))*3 + flab(ww*8 + (m & 7));
    }
    unsigned short* pl = p_lds + h*4608;
    #pragma unroll
    for (int i = 0; i < 4; ++i) {
        #pragma unroll
        for (int rg = 0; rg < 4; ++rg) {
            int n = i*16 + quad*4 + rg;
            int rn = n >> 3, cn = n & 7;
            int labn = flab(wh*8 + rn)*3 + flab(ww*8 + cn);
            float vals[4];
            float vmax = -1e30f;
            #pragma unroll
            for (int j = 0; j < 4; ++j) {
                int m = j*16 + lrow;
                int idx = ((rn - (m >> 3) + 7)*15 + (cn - (m & 7) + 7))*6 + h;
                float val = s[i][j][rg] + rpb_s[idx];
                if (labn != labm[j]) val -= 100.f;
                vals[j] = val;
                vmax = fmaxf(vmax, val);
            }
            #pragma unroll
            for (int o = 1; o < 16; o <<= 1) vmax = fmaxf(vmax, __shfl_xor(vmax, o));
            float sum = 0.f;
            #pragma unroll
            for (int j = 0; j < 4; ++j) { vals[j] = __expf(vals[j] - vmax); sum += vals[j]; }
            #pragma unroll
            for (int o = 1; o < 16; o <<= 1) sum += __shfl_xor(sum, o);
            float inv = 1.f / sum;
            #pragma unroll
            for (int j = 0; j < 4; ++j) pl[n*72 + j*16 + lrow] = f2bf(vals[j]*inv);
        }
    }
    __syncthreads();

    f32x4 oacc[4][2];
    #pragma unroll
    for (int i = 0; i < 4; ++i) { oacc[i][0] = zz; oacc[i][1] = zz; }
    #pragma unroll
    for (int kc = 0; kc < 2; ++kc) {
        s16x8 vf[2];
        #pragma unroll
        for (int jd = 0; jd < 2; ++jd)
            vf[jd] = *(const s16x8*)(vb + (jd*16+lrow)*64 + kc*32 + quad*8);
        #pragma unroll
        for (int i = 0; i < 4; ++i) {
            s16x8 pf = *(const s16x8*)(pl + (i*16+lrow)*72 + kc*32 + quad*8);
            #pragma unroll
            for (int jd = 0; jd < 2; ++jd)
                oacc[i][jd] = __builtin_amdgcn_mfma_f32_16x16x32_bf16(pf, vf[jd], oacc[i][jd], 0, 0, 0);
        }
    }
    unsigned short* ob = ao + (size_t)b_*12288 + h*32;
    #pragma unroll
    for (int i = 0; i < 4; ++i)
        #pragma unroll
        for (int jd = 0; jd < 2; ++jd)
            #pragma unroll
            for (int rg = 0; rg < 4; ++rg) {
                int n = i*16 + quad*4 + rg;
                ob[(size_t)n*192 + jd*16 + lrow] = f2bf(oacc[i][jd][rg]);
            }
}

// =====================================================================
// 64x192 pipelined GEMM mainloop for projln: async16 + swizzle + 2-buffer.
// =====================================================================
__device__ __forceinline__ void mm64x192(
    const unsigned short* __restrict__ A, const unsigned short* __restrict__ W,
    size_t m0, unsigned short* As, unsigned short* Bs, f32x4 (&acc)[12])
{
    const int tid = threadIdx.x, wv = tid>>6, lane = tid&63;
    const int lrow = lane&15, quad = lane>>4;
    const int grow = lane>>2;                       // row within 16-row group
    const int gcb  = (lane&3) ^ ((lane>>3)&3);      // inverse-swizzled src col-block
    #pragma unroll
    for (int j=0;j<12;++j) acc[j] = (f32x4){0.f,0.f,0.f,0.f};

    const unsigned short* Ab = A + (m0 + grow)*192 + gcb*8;
    const unsigned short* Wb = W + (size_t)grow*192 + gcb*8;

    auto issue = [&](int k0, unsigned short* Ad, unsigned short* Bd) {
        async16(Ab + (size_t)(wv*16)*192 + k0,     Ad + wv*512);     // A: 4 groups
        async16(Wb + (size_t)(wv*16)*192 + k0,     Bd + wv*512);     // B: 12 groups
        async16(Wb + (size_t)((wv+4)*16)*192 + k0, Bd + (wv+4)*512);
        async16(Wb + (size_t)((wv+8)*16)*192 + k0, Bd + (wv+8)*512);
    };
    issue(0, As, Bs);
    int cur = 0;
    for (int k0=0; k0<192; k0+=32) {
        __syncthreads();                       // tile cur landed; prev reads done
        if (k0+32 < 192) issue(k0+32, As + (cur^1)*2048, Bs + (cur^1)*6144);
        const unsigned short* Ac = As + cur*2048;
        const unsigned short* Bc = Bs + cur*6144;
        const int rs = (quad ^ ((lrow>>1)&3)) << 3;
        s16x8 af = *(const s16x8*)(Ac + (wv*16+lrow)*32 + rs);
        #pragma unroll
        for (int j=0;j<12;++j) {
            s16x8 bf = *(const s16x8*)(Bc + (j*16+lrow)*32 + rs);
            acc[j] = __builtin_amdgcn_mfma_f32_16x16x32_bf16(af, bf, acc[j], 0, 0, 0);
        }
        cur ^= 1;
    }
}

// =====================================================================
// proj GEMM (full O=192) + window-reverse/roll + residual + LN2, fused.
// Writes x1 fp32 (token layout) + xln2 in BLOCKED layout:
// xln2[mt][ks][128][32] pre-swizzled; m-tile stride 24576 shorts.
// =====================================================================
__global__ __launch_bounds__(256) void projln_kernel(
    const unsigned short* __restrict__ A, const unsigned short* __restrict__ W,
    const float* __restrict__ pbias, const float* __restrict__ x,
    const float* __restrict__ g2, const float* __restrict__ b2,
    float* __restrict__ x1, unsigned short* __restrict__ xln2b)
{
    __shared__ __attribute__((aligned(16))) char smem[32768];
    unsigned short* As = (unsigned short*)smem;             // 2 x 4KB
    unsigned short* Bs = (unsigned short*)(smem + 8192);    // 2 x 12KB
    const int b_ = blockIdx.x;
    const int tid = threadIdx.x, wv = tid>>6, lane = tid&63;
    const int lrow = lane&15, quad = lane>>4;
    const size_t m0 = (size_t)b_*64;

    f32x4 acc[12];
    mm64x192(A, W, m0, As, Bs, acc);
    __syncthreads();

    const int bb = b_>>8, wi = b_&255, wh = wi>>4, ww = wi&15;
    float bv[12], gv[12], b2v[12];
    #pragma unroll
    for (int j=0;j<12;++j) {
        bv[j]  = pbias[j*16+lrow];
        gv[j]  = g2[j*16+lrow];
        b2v[j] = b2[j*16+lrow];
    }
    unsigned short* T = (unsigned short*)smem;   // 64x200 (25.6KB <= 32KB)
    #pragma unroll
    for (int rg=0;rg<4;++rg) {
        int n2 = wv*16 + quad*4 + rg;
        int r = n2>>3, c = n2&7;
        int hh = (wh*8+r+4)&127, wp = (ww*8+c+4)&127;   // roll(+4) back
        size_t tok = ((size_t)bb*128+hh)*128 + wp;
        float xv[12];
        float s = 0.f;
        #pragma unroll
        for (int j=0;j<12;++j) {
            float t = acc[j][rg] + bv[j] + x[tok*192 + j*16 + lrow];
            xv[j] = t; s += t;
        }
        #pragma unroll
        for (int o=1;o<16;o<<=1) s += __shfl_xor(s, o);
        float mu = s*(1.0f/192.0f);
        float qv = 0.f;
        #pragma unroll
        for (int j=0;j<12;++j){ float d = xv[j]-mu; qv += d*d; }
        #pragma unroll
        for (int o=1;o<16;o<<=1) qv += __shfl_xor(qv, o);
        float rstd = rsqrtf(qv*(1.0f/192.0f) + 1e-5f);
        #pragma unroll
        for (int j=0;j<12;++j) {
            x1[tok*192 + j*16 + lrow] = xv[j];
            T[n2*200 + j*16 + lrow] = f2bf((xv[j]-mu)*rstd*gv[j] + b2v[j]);
        }
    }
    __syncthreads();
    #pragma unroll
    for (int t=0;t<6;++t) {
        int cid = tid + t*256;                   // 0..1535
        int n2 = cid/24, blk = cid%24;
        int r = n2>>3, c = n2&7;
        int hh = (wh*8+r+4)&127, wp = (ww*8+c+4)&127;
        size_t tok = ((size_t)bb*128+hh)*128 + wp;
        int row = (int)(tok & 127);
        int ks = blk>>2, kb = blk&3;
        int sw = (kb ^ ((row>>1)&3)) << 3;
        *(int4*)(xln2b + (tok>>7)*24576 + ks*4096 + row*32 + sw) =
            *(const int4*)(T + n2*200 + blk*8);
    }
}

// =====================================================================
// FUSED MLP v6: v5's 32-row/4-wave structure with v3's PROVEN register
// budget. v5's __launch_bounds__(256,6) forced VGPR<=85 -> accumulator
// spill (FETCH 294MB/WRITE 359MB, dur 281us). (256,4) = cap 128, the
// budget under which this exact per-thread working set compiled to 64
// VGPR spill-free (v3). LDS 24KB -> up to 6 blocks/CU (24 waves, 75%).
// Grid 4096; per-wave tiles identical to v3. h never hits HBM.
// =====================================================================
__global__ __launch_bounds__(256, 4) void mlp_kernel(
    const unsigned short* __restrict__ Ablk,   // xln2b [1024][6][128][32] swizzled
    const unsigned short* __restrict__ W1b,    // [4][6][192][32]
    const float* __restrict__ fc1b,
    const unsigned short* __restrict__ W2b,    // [4][24][48][32]
    const float* __restrict__ fc2b,
    const float* __restrict__ x1, float* __restrict__ out)
{
    __shared__ __attribute__((aligned(16))) unsigned short Ald[6*1024];   // 12KB
    __shared__ __attribute__((aligned(16))) unsigned short Hld[6*1024];   // 12KB
    const int b_ = blockIdx.x;
    const int mt = b_>>2, sub = b_&3;              // 32-row slice of the 128-row m-tile
    const int tid = threadIdx.x, wv = tid>>6, lane = tid&63;
    const int lrow = lane&15, quad = lane>>4;
    const int c0 = wv*48;
    const int rs = (quad ^ ((lrow>>1)&3)) << 3;    // swizzled col-block (shorts)

    // ---- stage A: 32 rows x 192 = 12 chunks x 1KB, linear async16 ----
    {
        const unsigned short* src = Ablk + (size_t)mt*24576 + sub*1024 + lane*8;
        #pragma unroll
        for (int r=0;r<3;++r) {
            int c = r*4 + wv;                      // chunk 0..11: ks=c>>1, half=c&1
            async16(src + (c>>1)*4096 + (c&1)*512, Ald + c*512);
        }
    }

    // fc1 bias (all 4 chunks upfront: 12 scalars, L2-hot)
    float bv1[4][3];
    #pragma unroll
    for (int oc=0;oc<4;++oc)
        #pragma unroll
        for (int j=0;j<3;++j) bv1[oc][j] = fc1b[oc*192 + c0 + j*16 + lrow];

    f32x4 a2[2][3];
    #pragma unroll
    for (int i=0;i<2;++i)
        #pragma unroll
        for (int j=0;j<3;++j) a2[i][j] = (f32x4){0.f,0.f,0.f,0.f};

    // rolling fc1 weight prefetch: first fragments of oc=0, ks=0
    const unsigned short* w1base = W1b + (size_t)c0*32 + quad*8;
    s16x8 b1c[3];
    #pragma unroll
    for (int j=0;j<3;++j) b1c[j] = *(const s16x8*)(w1base + (j*16 + lrow)*32);

    __syncthreads();                               // A landed

    for (int oc=0; oc<4; ++oc) {
        const unsigned short* w1p = w1base + (size_t)(oc*6)*6144;
        // ---- fc1 partial: 32 rows x h-cols oc*192+c0..+47, K=192 ----
        f32x4 a1[2][3];
        #pragma unroll
        for (int i=0;i<2;++i)
            #pragma unroll
            for (int j=0;j<3;++j) a1[i][j] = (f32x4){0.f,0.f,0.f,0.f};
        #pragma unroll
        for (int ks=0;ks<6;++ks) {
            s16x8 b1n[3];
            if (ks < 5) {
                #pragma unroll
                for (int j=0;j<3;++j)
                    b1n[j] = *(const s16x8*)(w1p + (size_t)(ks+1)*6144 + (j*16 + lrow)*32);
            }
            s16x8 af[2];
            #pragma unroll
            for (int i=0;i<2;++i)
                af[i] = *(const s16x8*)(Ald + ks*1024 + (i*16 + lrow)*32 + rs);
            #pragma unroll
            for (int i=0;i<2;++i)
                #pragma unroll
                for (int j=0;j<3;++j)
                    a1[i][j] = __builtin_amdgcn_mfma_f32_16x16x32_bf16(af[i], b1c[j], a1[i][j], 0, 0, 0);
            if (ks < 5) { b1c[0]=b1n[0]; b1c[1]=b1n[1]; b1c[2]=b1n[2]; }
        }

        // prefetch fc2's first fragments (independent of Hld; lands under GELU)
        const unsigned short* w2p = W2b + (size_t)(wv*24 + oc*6)*1536 + quad*8;
        s16x8 b2c[3];
        #pragma unroll
        for (int j=0;j<3;++j) b2c[j] = *(const s16x8*)(w2p + (j*16 + lrow)*32);
        // prefetch next oc's fc1 first fragments (lands under GELU + fc2)
        if (oc < 3) {
            #pragma unroll
            for (int j=0;j<3;++j)
                b1c[j] = *(const s16x8*)(w1base + (size_t)((oc+1)*6)*6144 + (j*16 + lrow)*32);
        }

        if (oc) __syncthreads();                   // prev fc2 done reading Hld

        // ---- bias + tanh-GELU -> Hld ([6][32][32] swizzled) ----
        #pragma unroll
        for (int i=0;i<2;++i)
            #pragma unroll
            for (int j=0;j<3;++j)
                #pragma unroll
                for (int rg=0;rg<4;++rg) {
                    int row = i*16 + quad*4 + rg;  // local row 0..31
                    int o = c0 + j*16 + lrow;      // 0..191 within chunk
                    float v = a1[i][j][rg] + bv1[oc][j];
                    float v2 = v*v;
                    float z = v*(1.5957691216057308f + 0.07135481627f*v2);
                    float r = v * __builtin_amdgcn_rcpf(1.f + __expf(-z));
                    int ksh = o>>5, c5 = o&31;
                    Hld[ksh*1024 + row*32 + (((c5>>3) ^ ((row>>1)&3))<<3) + (c5&7)] = f2bf(r);
                }
        __syncthreads();                           // H visible

        // ---- fc2 accumulate: K-slice oc*192..+191 from Hld ----
        #pragma unroll
        for (int ksl=0;ksl<6;++ksl) {
            s16x8 b2n[3];
            if (ksl < 5) {
                #pragma unroll
                for (int j=0;j<3;++j)
                    b2n[j] = *(const s16x8*)(w2p + (size_t)(ksl+1)*1536 + (j*16 + lrow)*32);
            }
            s16x8 af2[2];
            #pragma unroll
            for (int i=0;i<2;++i)
                af2[i] = *(const s16x8*)(Hld + ksl*1024 + (i*16 + lrow)*32 + rs);
            #pragma unroll
            for (int i=0;i<2;++i)
                #pragma unroll
                for (int j=0;j<3;++j)
                    a2[i][j] = __builtin_amdgcn_mfma_f32_16x16x32_bf16(af2[i], b2c[j], a2[i][j], 0, 0, 0);
            if (ksl < 5) { b2c[0]=b2n[0]; b2c[1]=b2n[1]; b2c[2]=b2n[2]; }
        }
    }

    // ---- bias + residual -> out ----
    {
        float bv2[3];
        #pragma unroll
        for (int j=0;j<3;++j) bv2[j] = fc2b[c0 + j*16 + lrow];
        #pragma unroll
        for (int i=0;i<2;++i)
            #pragma unroll
            for (int j=0;j<3;++j)
                #pragma unroll
                for (int rg=0;rg<4;++rg) {
                    size_t grow = (size_t)mt*128 + sub*32 + i*16 + quad*4 + rg;
                    size_t ad = grow*192 + c0 + j*16 + lrow;
                    out[ad] = a2[i][j][rg] + bv2[j] + x1[ad];
                }
    }
}

extern "C" void kernel_launch(void* const* d_in, const int* in_sizes, int n_in,
                              void* d_out, int out_size, void* d_ws, size_t ws_size,
                              hipStream_t stream)
{
    const float* x      = (const float*)d_in[0];
    const float* g1     = (const float*)d_in[1];
    const float* b1     = (const float*)d_in[2];
    const float* qkv_w  = (const float*)d_in[3];
    const float* qkv_b  = (const float*)d_in[4];
    const float* rpb    = (const float*)d_in[5];
    const float* proj_w = (const float*)d_in[6];
    const float* proj_b = (const float*)d_in[7];
    const float* g2     = (const float*)d_in[8];
    const float* b2     = (const float*)d_in[9];
    const float* fc1_w  = (const float*)d_in[10];
    const float* fc1_b  = (const float*)d_in[11];
    const float* fc2_w  = (const float*)d_in[12];
    const float* fc2_b  = (const float*)d_in[13];
    float* out = (float*)d_out;
    char* ws = (char*)d_ws;

    if (ws_size < 353206272ULL) return;

    unsigned short* qbuf  = (unsigned short*)(ws + 0);          // 50.3MB
    unsigned short* kbuf  = (unsigned short*)(ws + 50331648);   // 50.3MB
    unsigned short* vbuf  = (unsigned short*)(ws + 100663296);  // 50.3MB (vT)
    unsigned short* attnO = (unsigned short*)(ws + 150994944);  // 50.3MB
    float*          x1    = (float*)        (ws + 201326592);   // 100.7MB
    unsigned short* xln2  = (unsigned short*)(ws + 301989888);  // 50.3MB (blocked, 1024x24576)
    unsigned short* wq    = (unsigned short*)(ws + 352321536);
    unsigned short* wp    = (unsigned short*)(ws + 352321536 + 221184);
    unsigned short* w1b   = (unsigned short*)(ws + 352321536 + 221184 + 73728);
    unsigned short* w2b   = (unsigned short*)(ws + 352321536 + 221184 + 73728 + 294912);

    wconv_all<<<576, 256, 0, stream>>>(qkv_w, proj_w, fc1_w, fc2_w, wq, wp, w1b, w2b);
    lnqkv_kernel<<<2048, 256, 0, stream>>>(x, g1, b1, wq, qkv_b, qbuf, kbuf, vbuf);
    attn_kernel<<<2048, 384, 0, stream>>>(qbuf, kbuf, vbuf, rpb, attnO);
    projln_kernel<<<2048, 256, 0, stream>>>(attnO, wp, proj_b, x, g2, b2, x1, xln2);
    mlp_kernel<<<4096, 256, 0, stream>>>(xln2, w1b, fc1_b, w2b, fc2_b, x1, out);
}